// Round 1
// baseline (229.341 us; speedup 1.0000x reference)
//
#include <hip/hip_runtime.h>
#include <math.h>

#define B_  16
#define N_  512
#define C_  384
#define K_  64
#define NN_ (N_*N_)   // 262144

// ---------------------------------------------------------------------------
// helpers
// ---------------------------------------------------------------------------
__device__ __forceinline__ void fma4(float4& c, float s, const float4& v) {
    c.x = fmaf(s, v.x, c.x);
    c.y = fmaf(s, v.y, c.y);
    c.z = fmaf(s, v.z, c.z);
    c.w = fmaf(s, v.w, c.w);
}

// ---------------------------------------------------------------------------
// 1) q[b,c] = sum_n x[b,n,c]   (mean's /N cancels inside l2norm -> skip it)
//    grid (32, 16), block 384.  Each block sums 16 rows, atomicAdd into q.
//    q must be zeroed beforehand (hipMemsetAsync in kernel_launch).
// ---------------------------------------------------------------------------
__global__ __launch_bounds__(384) void mean_kernel(const float* __restrict__ x,
                                                   float* __restrict__ q) {
    const int b = blockIdx.y;
    const int s = blockIdx.x;      // n-chunk of 16
    const int c = threadIdx.x;     // 0..383
    const float* xp = x + ((size_t)(b * N_ + s * 16)) * C_ + c;
    float acc = 0.f;
#pragma unroll
    for (int i = 0; i < 16; ++i) acc += xp[(size_t)i * C_];
    atomicAdd(&q[b * C_ + c], acc);
}

// ---------------------------------------------------------------------------
// 2) attn[b,k] = softmax_k( (q . centers[:,k]) / (|q| * |centers[:,k]|) )
//    grid 16, block 64 (one wave per batch).
// ---------------------------------------------------------------------------
__global__ __launch_bounds__(64) void attn_kernel(const float* __restrict__ q,
                                                  const float* __restrict__ centers,
                                                  float* __restrict__ attn) {
    const int b = blockIdx.x;
    const int k = threadIdx.x;     // 0..63
    const float* qb = q + b * C_;

    // |q|^2 : lane-parallel partial then butterfly reduce
    float qn2 = 0.f;
    for (int c = k; c < C_; c += 64) { float v = qb[c]; qn2 += v * v; }
#pragma unroll
    for (int off = 32; off > 0; off >>= 1) qn2 += __shfl_xor(qn2, off);
    const float qnorm = fmaxf(sqrtf(qn2), 1e-12f);

    // per-lane: dot(q, centers[:,k]) and |centers[:,k]|^2
    float dot = 0.f, cn2 = 0.f;
    for (int c = 0; c < C_; ++c) {
        float sv = centers[c * K_ + k];   // coalesced across lanes
        float qc = qb[c];                 // broadcast
        dot = fmaf(qc, sv, dot);
        cn2 = fmaf(sv, sv, cn2);
    }
    const float logit = dot / (qnorm * fmaxf(sqrtf(cn2), 1e-12f));

    // softmax across the 64 lanes
    float m = logit;
#pragma unroll
    for (int off = 32; off > 0; off >>= 1) m = fmaxf(m, __shfl_xor(m, off));
    const float e = expf(logit - m);
    float ssum = e;
#pragma unroll
    for (int off = 32; off > 0; off >>= 1) ssum += __shfl_xor(ssum, off);
    attn[b * K_ + k] = e / ssum;
}

// ---------------------------------------------------------------------------
// 3) tm[b,:,:] = sum_k attn[b,k] * tran_ms[k,:,:]
//    Read tran_ms once; keep all 16 batch accumulators in registers.
//    grid 256, block 256; each thread owns one float4 position of (n,m).
// ---------------------------------------------------------------------------
__global__ __launch_bounds__(256) void tm_kernel(const float* __restrict__ tran,
                                                 const float* __restrict__ attn,
                                                 float* __restrict__ tm) {
    __shared__ float a_s[B_ * K_];   // 1024 floats
    const int tid = threadIdx.x;
    for (int i = tid; i < B_ * K_; i += 256) a_s[i] = attn[i];
    __syncthreads();

    const size_t j = ((size_t)blockIdx.x * 256 + tid) * 4;
    float4 acc[B_];
#pragma unroll
    for (int b = 0; b < B_; ++b) acc[b] = make_float4(0.f, 0.f, 0.f, 0.f);

    for (int k = 0; k < K_; ++k) {
        const float4 t = *(const float4*)(tran + (size_t)k * NN_ + j);
#pragma unroll
        for (int b = 0; b < B_; ++b) fma4(acc[b], a_s[b * K_ + k], t);
    }
#pragma unroll
    for (int b = 0; b < B_; ++b)
        *(float4*)(tm + (size_t)b * NN_ + j) = acc[b];
}

// ---------------------------------------------------------------------------
// 4) xw[r,n] = sum_m x[r,m] * W[n,m]        (x @ W^T), r in [0,8192)
//    64x64 tile, BK=16, 256 threads, 4x4 microtile.
// ---------------------------------------------------------------------------
#define PAD 68
__global__ __launch_bounds__(256) void xw_kernel(const float* __restrict__ x,
                                                 const float* __restrict__ w,
                                                 float* __restrict__ xw) {
    __shared__ float As[16][PAD];
    __shared__ float Bs[16][PAD];
    const int tid = threadIdx.x;
    const int tx = tid & 15, ty = tid >> 4;
    const int row0 = blockIdx.x * 64;
    const int col0 = blockIdx.y * 64;

    const int lr = tid >> 2;          // 0..63
    const int lk = (tid & 3) * 4;     // 0,4,8,12

    float4 acc[4];
#pragma unroll
    for (int i = 0; i < 4; ++i) acc[i] = make_float4(0.f, 0.f, 0.f, 0.f);

    for (int k0 = 0; k0 < C_; k0 += 16) {
        const float4 av = *(const float4*)(x + (size_t)(row0 + lr) * C_ + k0 + lk);
        const float4 bv = *(const float4*)(w + (size_t)(col0 + lr) * C_ + k0 + lk);
        __syncthreads();
        As[lk + 0][lr] = av.x; As[lk + 1][lr] = av.y;
        As[lk + 2][lr] = av.z; As[lk + 3][lr] = av.w;
        Bs[lk + 0][lr] = bv.x; Bs[lk + 1][lr] = bv.y;
        Bs[lk + 2][lr] = bv.z; Bs[lk + 3][lr] = bv.w;
        __syncthreads();
#pragma unroll
        for (int k = 0; k < 16; ++k) {
            const float4 a  = *(const float4*)(&As[k][ty * 4]);
            const float4 bb = *(const float4*)(&Bs[k][tx * 4]);
            fma4(acc[0], a.x, bb);
            fma4(acc[1], a.y, bb);
            fma4(acc[2], a.z, bb);
            fma4(acc[3], a.w, bb);
        }
    }
#pragma unroll
    for (int i = 0; i < 4; ++i)
        *(float4*)(xw + (size_t)(row0 + ty * 4 + i) * C_ + col0 + tx * 4) = acc[i];
}

// ---------------------------------------------------------------------------
// 5) out[b,n,c] = sum_m tm[b,n,m] * xw[b,m,c] + bias[c]
//    grid (8, 6, 16); same 64x64 tile structure, K=512.
// ---------------------------------------------------------------------------
__global__ __launch_bounds__(256) void out_kernel(const float* __restrict__ tm,
                                                  const float* __restrict__ xw,
                                                  const float* __restrict__ bias,
                                                  float* __restrict__ out) {
    __shared__ float As[16][PAD];
    __shared__ float Bs[16][PAD];
    const int tid = threadIdx.x;
    const int tx = tid & 15, ty = tid >> 4;
    const int b = blockIdx.z;
    const int row0 = blockIdx.x * 64;
    const int col0 = blockIdx.y * 64;

    const float* A  = tm + (size_t)b * NN_;        // [512][512]
    const float* Bm = xw + (size_t)b * N_ * C_;    // [512][384]

    const int lr = tid >> 2;          // A loader: 0..63 rows
    const int lk = (tid & 3) * 4;     // A loader: k offset
    const int bk = tid >> 4;          // B loader: 0..15 k rows
    const int bn = (tid & 15) * 4;    // B loader: col offset

    float4 acc[4];
#pragma unroll
    for (int i = 0; i < 4; ++i) acc[i] = make_float4(0.f, 0.f, 0.f, 0.f);

    for (int k0 = 0; k0 < N_; k0 += 16) {
        const float4 av = *(const float4*)(A + (size_t)(row0 + lr) * N_ + k0 + lk);
        const float4 bv = *(const float4*)(Bm + (size_t)(k0 + bk) * C_ + col0 + bn);
        __syncthreads();
        As[lk + 0][lr] = av.x; As[lk + 1][lr] = av.y;
        As[lk + 2][lr] = av.z; As[lk + 3][lr] = av.w;
        *(float4*)(&Bs[bk][bn]) = bv;
        __syncthreads();
#pragma unroll
        for (int k = 0; k < 16; ++k) {
            const float4 a  = *(const float4*)(&As[k][ty * 4]);
            const float4 bb = *(const float4*)(&Bs[k][tx * 4]);
            fma4(acc[0], a.x, bb);
            fma4(acc[1], a.y, bb);
            fma4(acc[2], a.z, bb);
            fma4(acc[3], a.w, bb);
        }
    }

    const float4 bias4 = *(const float4*)(bias + col0 + tx * 4);
#pragma unroll
    for (int i = 0; i < 4; ++i) {
        float4 v = acc[i];
        v.x += bias4.x; v.y += bias4.y; v.z += bias4.z; v.w += bias4.w;
        *(float4*)(out + ((size_t)(b * N_) + row0 + ty * 4 + i) * C_ + col0 + tx * 4) = v;
    }
}

// ---------------------------------------------------------------------------
// launch
// ---------------------------------------------------------------------------
extern "C" void kernel_launch(void* const* d_in, const int* in_sizes, int n_in,
                              void* d_out, int out_size, void* d_ws, size_t ws_size,
                              hipStream_t stream) {
    const float* x       = (const float*)d_in[0];   // [16,512,384]
    const float* centers = (const float*)d_in[1];   // [384,64]
    const float* tran    = (const float*)d_in[2];   // [64,512,512]
    const float* proj_w  = (const float*)d_in[3];   // [384,384]
    const float* proj_b  = (const float*)d_in[4];   // [384]
    float* out = (float*)d_out;                     // [16,512,384]

    float* ws   = (float*)d_ws;
    float* q    = ws;                               // 16*384   = 6144
    float* attn = ws + 6144;                        // 16*64    = 1024
    float* tmw  = ws + 8192;                        // 16*512*512 = 4194304
    float* xww  = ws + 8192 + 4194304;              // 16*512*384 = 3145728

    // zero the q accumulator (ws is re-poisoned to 0xAA before every launch)
    hipMemsetAsync(q, 0, (size_t)B_ * C_ * sizeof(float), stream);

    mean_kernel<<<dim3(32, 16), 384, 0, stream>>>(x, q);
    attn_kernel<<<16, 64, 0, stream>>>(q, centers, attn);
    tm_kernel<<<256, 256, 0, stream>>>(tran, attn, tmw);
    xw_kernel<<<dim3(128, 6), 256, 0, stream>>>(x, proj_w, xww);
    out_kernel<<<dim3(8, 6, 16), 256, 0, stream>>>(tmw, xww, proj_b, out);
}

// Round 2
// 158.908 us; speedup vs baseline: 1.4432x; 1.4432x over previous
//
#include <hip/hip_runtime.h>
#include <math.h>
#include <stdint.h>

#define B_  16
#define N_  512
#define C_  384
#define K_  64
#define NN_ (N_*N_)   // 262144

typedef short bf16x8 __attribute__((ext_vector_type(8)));
typedef float f32x4  __attribute__((ext_vector_type(4)));

// fp32 -> bf16 round-to-nearest-even (no NaN handling needed: inputs are finite)
__device__ __forceinline__ unsigned short f2bf(float f) {
    union { float f; unsigned u; } v; v.f = f;
    unsigned r = v.u + 0x7FFF + ((v.u >> 16) & 1);
    return (unsigned short)(r >> 16);
}

// async 16-B global -> LDS (lane-contiguous LDS dest required)
__device__ __forceinline__ void gl_lds16(const void* g, void* l) {
    __builtin_amdgcn_global_load_lds(
        (const __attribute__((address_space(1))) unsigned*)g,
        (__attribute__((address_space(3))) unsigned*)l, 16, 0, 0);
}

// ---------------------------------------------------------------------------
// 1) q[b,c] = sum_n x[b,n,c]  (the /N cancels in l2norm) + emit x as bf16
// ---------------------------------------------------------------------------
__global__ __launch_bounds__(384) void mean_kernel(const float* __restrict__ x,
                                                   float* __restrict__ q,
                                                   unsigned short* __restrict__ xb) {
    const int b = blockIdx.y;
    const int s = blockIdx.x;      // n-chunk of 16
    const int c = threadIdx.x;     // 0..383
    const size_t base = ((size_t)(b * N_ + s * 16)) * C_ + c;
    const float* xp = x + base;
    unsigned short* xo = xb + base;
    float acc = 0.f;
#pragma unroll
    for (int i = 0; i < 16; ++i) {
        float v = xp[(size_t)i * C_];
        acc += v;
        xo[(size_t)i * C_] = f2bf(v);
    }
    atomicAdd(&q[b * C_ + c], acc);
}

// ---------------------------------------------------------------------------
// 1b) proj_w -> bf16 (row-major [n][k], directly B-operand stageable)
// ---------------------------------------------------------------------------
__global__ __launch_bounds__(256) void wconv_kernel(const float* __restrict__ w,
                                                    unsigned short* __restrict__ wb) {
    const int i = (blockIdx.x * 256 + threadIdx.x) * 4;   // 144 blocks cover 147456
    const float4 v = *(const float4*)(w + i);
    unsigned u0 = ((unsigned)f2bf(v.y) << 16) | f2bf(v.x);
    unsigned u1 = ((unsigned)f2bf(v.w) << 16) | f2bf(v.z);
    *(uint2*)(wb + i) = make_uint2(u0, u1);
}

// ---------------------------------------------------------------------------
// 2) attn[b,k] = softmax_k( (q . centers[:,k]) / (|q| |centers[:,k]|) )
// ---------------------------------------------------------------------------
__global__ __launch_bounds__(64) void attn_kernel(const float* __restrict__ q,
                                                  const float* __restrict__ centers,
                                                  float* __restrict__ attn) {
    const int b = blockIdx.x;
    const int k = threadIdx.x;
    const float* qb = q + b * C_;

    float qn2 = 0.f;
    for (int c = k; c < C_; c += 64) { float v = qb[c]; qn2 += v * v; }
#pragma unroll
    for (int off = 32; off > 0; off >>= 1) qn2 += __shfl_xor(qn2, off);
    const float qnorm = fmaxf(sqrtf(qn2), 1e-12f);

    float dot = 0.f, cn2 = 0.f;
    for (int c = 0; c < C_; ++c) {
        float sv = centers[c * K_ + k];
        float qc = qb[c];
        dot = fmaf(qc, sv, dot);
        cn2 = fmaf(sv, sv, cn2);
    }
    const float logit = dot / (qnorm * fmaxf(sqrtf(cn2), 1e-12f));

    float m = logit;
#pragma unroll
    for (int off = 32; off > 0; off >>= 1) m = fmaxf(m, __shfl_xor(m, off));
    const float e = expf(logit - m);
    float ssum = e;
#pragma unroll
    for (int off = 32; off > 0; off >>= 1) ssum += __shfl_xor(ssum, off);
    attn[b * K_ + k] = e / ssum;
}

// ---------------------------------------------------------------------------
// 3) tm[b,:,:] = sum_k attn[b,k] * tran_ms[k,:,:]  -> bf16 output
// ---------------------------------------------------------------------------
__global__ __launch_bounds__(256) void tm_kernel(const float* __restrict__ tran,
                                                 const float* __restrict__ attn,
                                                 unsigned short* __restrict__ tmb) {
    __shared__ float a_s[B_ * K_];
    const int tid = threadIdx.x;
    for (int i = tid; i < B_ * K_; i += 256) a_s[i] = attn[i];
    __syncthreads();

    const size_t j = ((size_t)blockIdx.x * 256 + tid) * 4;
    float4 acc[B_];
#pragma unroll
    for (int b = 0; b < B_; ++b) acc[b] = make_float4(0.f, 0.f, 0.f, 0.f);

    for (int k = 0; k < K_; ++k) {
        const float4 t = *(const float4*)(tran + (size_t)k * NN_ + j);
#pragma unroll
        for (int b = 0; b < B_; ++b) {
            float s = a_s[b * K_ + k];
            acc[b].x = fmaf(s, t.x, acc[b].x);
            acc[b].y = fmaf(s, t.y, acc[b].y);
            acc[b].z = fmaf(s, t.z, acc[b].z);
            acc[b].w = fmaf(s, t.w, acc[b].w);
        }
    }
#pragma unroll
    for (int b = 0; b < B_; ++b) {
        unsigned u0 = ((unsigned)f2bf(acc[b].y) << 16) | f2bf(acc[b].x);
        unsigned u1 = ((unsigned)f2bf(acc[b].w) << 16) | f2bf(acc[b].z);
        *(uint2*)(tmb + (size_t)b * NN_ + j) = make_uint2(u0, u1);
    }
}

// ---------------------------------------------------------------------------
// 4) xw = x @ W^T  (bf16 MFMA), output TRANSPOSED per batch: xwT[b][c][m] bf16
//    A = xb [8192][384] (row=r, k-contig), B staged from wb rows [n][k].
//    grid (128, 6), block 256 (4 waves, 2x2 of 32x32 wave tiles).
// ---------------------------------------------------------------------------
__global__ __launch_bounds__(256) void xw_mfma(const unsigned short* __restrict__ Xb,
                                               const unsigned short* __restrict__ Wb,
                                               unsigned short* __restrict__ xwT) {
    __shared__ unsigned short As[64 * 64];
    __shared__ unsigned short Bs[64 * 64];
    __shared__ float T[4][32 * 35];   // per-wave transpose staging, pad 35

    const int tid  = threadIdx.x;
    const int row0 = blockIdx.x * 64;
    const int col0 = blockIdx.y * 64;
    const int lane = tid & 63;
    const int w    = tid >> 6;
    const int wm   = w & 1, wn = w >> 1;
    const int quad = lane >> 4, l15 = lane & 15;

    const int sm = tid >> 3;   // staging row within half-tile
    const int sc = tid & 7;    // staging chunk slot

    f32x4 acc[2][2] = {};

    for (int k0 = 0; k0 < C_; k0 += 64) {
        __syncthreads();
#pragma unroll
        for (int p = 0; p < 2; ++p) {
            const int m  = p * 32 + sm;
            const int gc = sc ^ (m & 7);          // XOR-swizzled source chunk
            gl_lds16(Xb + (size_t)(row0 + m) * C_ + k0 + gc * 8,
                     As + (p * 256 + tid) * 8);
            gl_lds16(Wb + (size_t)(col0 + m) * C_ + k0 + gc * 8,
                     Bs + (p * 256 + tid) * 8);
        }
        __syncthreads();
#pragma unroll
        for (int kk = 0; kk < 2; ++kk) {
            bf16x8 afr[2], bfr[2];
#pragma unroll
            for (int mt = 0; mt < 2; ++mt) {
                const int mr = wm * 32 + mt * 16 + l15;
                const int kc = (kk * 4 + quad) ^ (mr & 7);
                afr[mt] = *(const bf16x8*)(As + mr * 64 + kc * 8);
            }
#pragma unroll
            for (int nt = 0; nt < 2; ++nt) {
                const int nr = wn * 32 + nt * 16 + l15;
                const int kc = (kk * 4 + quad) ^ (nr & 7);
                bfr[nt] = *(const bf16x8*)(Bs + nr * 64 + kc * 8);
            }
#pragma unroll
            for (int mt = 0; mt < 2; ++mt)
#pragma unroll
                for (int nt = 0; nt < 2; ++nt)
                    acc[mt][nt] = __builtin_amdgcn_mfma_f32_16x16x32_bf16(
                        afr[mt], bfr[nt], acc[mt][nt], 0, 0, 0);
        }
    }

    // ---- transpose epilogue: write bf16 xwT[b][c][m] ----
#pragma unroll
    for (int mt = 0; mt < 2; ++mt)
#pragma unroll
        for (int nt = 0; nt < 2; ++nt)
#pragma unroll
            for (int r = 0; r < 4; ++r) {
                const int lrow = mt * 16 + quad * 4 + r;   // m dim
                const int lcol = nt * 16 + l15;            // c dim
                T[w][lrow * 35 + lcol] = acc[mt][nt][r];
            }
    __syncthreads();

    const int rw = row0 + wm * 32;
    const int b  = rw >> 9;
    const int m0 = rw & 511;
    const int c0 = col0 + wn * 32;
    unsigned short* dst = xwT + (size_t)b * C_ * N_;
#pragma unroll
    for (int i = 0; i < 8; ++i) {
        const int cl = i * 4 + quad;
        const int ml = l15 * 2;
        const float v0 = T[w][(ml + 0) * 35 + cl];
        const float v1 = T[w][(ml + 1) * 35 + cl];
        const unsigned u = ((unsigned)f2bf(v1) << 16) | f2bf(v0);
        *(unsigned*)(dst + (size_t)(c0 + cl) * N_ + m0 + ml) = u;
    }
}

// ---------------------------------------------------------------------------
// 5) out[b,n,c] = sum_m tm[b,n,m] * xw[b,m,c] + bias[c]   (bf16 MFMA, fp32 out)
//    A = tmb[b] [512][512]; B staged from xwT[b] rows [c][m].
//    grid (8, 6, 16), block 256.
// ---------------------------------------------------------------------------
__global__ __launch_bounds__(256) void out_mfma(const unsigned short* __restrict__ Ab,
                                                const unsigned short* __restrict__ Bt,
                                                const float* __restrict__ bias,
                                                float* __restrict__ out) {
    __shared__ unsigned short As[64 * 64];
    __shared__ unsigned short Bs[64 * 64];

    const int tid  = threadIdx.x;
    const int b    = blockIdx.z;
    const int row0 = blockIdx.x * 64;
    const int col0 = blockIdx.y * 64;
    const int lane = tid & 63;
    const int w    = tid >> 6;
    const int wm   = w & 1, wn = w >> 1;
    const int quad = lane >> 4, l15 = lane & 15;

    const unsigned short* Abase = Ab + (size_t)b * N_ * N_;
    const unsigned short* Bbase = Bt + (size_t)b * C_ * N_;

    const int sm = tid >> 3;
    const int sc = tid & 7;

    f32x4 acc[2][2] = {};

    for (int k0 = 0; k0 < N_; k0 += 64) {
        __syncthreads();
#pragma unroll
        for (int p = 0; p < 2; ++p) {
            const int m  = p * 32 + sm;
            const int gc = sc ^ (m & 7);
            gl_lds16(Abase + (size_t)(row0 + m) * N_ + k0 + gc * 8,
                     As + (p * 256 + tid) * 8);
            gl_lds16(Bbase + (size_t)(col0 + m) * N_ + k0 + gc * 8,
                     Bs + (p * 256 + tid) * 8);
        }
        __syncthreads();
#pragma unroll
        for (int kk = 0; kk < 2; ++kk) {
            bf16x8 afr[2], bfr[2];
#pragma unroll
            for (int mt = 0; mt < 2; ++mt) {
                const int mr = wm * 32 + mt * 16 + l15;
                const int kc = (kk * 4 + quad) ^ (mr & 7);
                afr[mt] = *(const bf16x8*)(As + mr * 64 + kc * 8);
            }
#pragma unroll
            for (int nt = 0; nt < 2; ++nt) {
                const int nr = wn * 32 + nt * 16 + l15;
                const int kc = (kk * 4 + quad) ^ (nr & 7);
                bfr[nt] = *(const bf16x8*)(Bs + nr * 64 + kc * 8);
            }
#pragma unroll
            for (int mt = 0; mt < 2; ++mt)
#pragma unroll
                for (int nt = 0; nt < 2; ++nt)
                    acc[mt][nt] = __builtin_amdgcn_mfma_f32_16x16x32_bf16(
                        afr[mt], bfr[nt], acc[mt][nt], 0, 0, 0);
        }
    }

    // epilogue: fp32 store + bias
#pragma unroll
    for (int nt = 0; nt < 2; ++nt) {
        const int c  = col0 + wn * 32 + nt * 16 + l15;
        const float bv = bias[c];
#pragma unroll
        for (int mt = 0; mt < 2; ++mt) {
            const int rbase = row0 + wm * 32 + mt * 16 + quad * 4;
#pragma unroll
            for (int r = 0; r < 4; ++r)
                out[((size_t)(b * N_ + rbase + r)) * C_ + c] = acc[mt][nt][r] + bv;
        }
    }
}

// ---------------------------------------------------------------------------
// launch
// ---------------------------------------------------------------------------
extern "C" void kernel_launch(void* const* d_in, const int* in_sizes, int n_in,
                              void* d_out, int out_size, void* d_ws, size_t ws_size,
                              hipStream_t stream) {
    const float* x       = (const float*)d_in[0];   // [16,512,384]
    const float* centers = (const float*)d_in[1];   // [384,64]
    const float* tran    = (const float*)d_in[2];   // [64,512,512]
    const float* proj_w  = (const float*)d_in[3];   // [384,384]
    const float* proj_b  = (const float*)d_in[4];   // [384]
    float* out = (float*)d_out;                     // [16,512,384]

    float* ws   = (float*)d_ws;
    float* q    = ws;                                // 6144 floats
    float* attn = ws + 6144;                         // 1024 floats
    unsigned short* tmb = (unsigned short*)(ws + 8192);          // 16*512*512 bf16
    unsigned short* xwT = tmb + (size_t)B_ * N_ * N_;            // 16*384*512 bf16
    unsigned short* xb  = xwT + (size_t)B_ * C_ * N_;            // 16*512*384 bf16
    unsigned short* wb  = xb  + (size_t)B_ * N_ * C_;            // 384*384 bf16

    hipMemsetAsync(q, 0, (size_t)B_ * C_ * sizeof(float), stream);

    mean_kernel<<<dim3(32, 16), 384, 0, stream>>>(x, q, xb);
    wconv_kernel<<<144, 256, 0, stream>>>(proj_w, wb);
    attn_kernel<<<16, 64, 0, stream>>>(q, centers, attn);
    tm_kernel<<<256, 256, 0, stream>>>(tran, attn, tmb);
    xw_mfma<<<dim3(128, 6), 256, 0, stream>>>(xb, wb, xwT);
    out_mfma<<<dim3(8, 6, 16), 256, 0, stream>>>(tmb, xwT, proj_b, out);
}